// Round 5
// baseline (47.626 us; speedup 1.0000x reference)
//
#include <hip/hip_runtime.h>

// SphericalHarmonicsLighting — B=16, V=262144 (2^18), QTR = V/4 = 65536
// DIAGNOSTIC ROUND (R5): identical compute kernel launched TWICE —
//   launch 1 -> d_out  (the real, validated output; byte-identical to R4 result)
//   launch 2 -> d_ws   (full-size dummy, never validated; falls back to d_out
//                       rewrite if ws too small — idempotent, still correct)
// Purpose: split "mixed-RW bytes floor" (dur ~2x = 52us) from "fixed per-replay
// overhead" (dur ~ 26 + ~17 = 43us) vs "warm-L3 headroom" (dur << 38us).
//
// Kernel body is EXACTLY R4's (26.33us standalone).

#define SH_V 262144
#define SH_B 16
#define QTR  65536

__global__ __launch_bounds__(256, 8) void sh_lighting_kernel(
    const float* __restrict__ normals,   // [B, V, 3]
    const float* __restrict__ sh,        // [27]
    float* __restrict__ out)             // [B, V, 3]
{
    __shared__ float nbr[3072];          // 12 KiB: 1024-vertex neighbor window

    const int tid  = threadIdx.x;
    const int lane = tid & 63;
    const int w    = tid >> 6;           // wave 0..3
    const int blk  = blockIdx.x;
    const int b    = blk >> 8;           // 256 u-blocks per batch image
    const int ublk = blk & 255;
    const int u0   = ublk << 8;          // u in [u0, u0+256)
    const int nb0  = u0 << 2;            // neighbor window base = 4*u0 (< V)

    const float* nbase = normals + (size_t)b * (SH_V * 3);

    // ---- wave-local coalesced staging: wave w stages window float4s [192w, 192w+192) ----
    {
        const float* src = nbase + (size_t)nb0 * 3;   // 12 KiB window
#pragma unroll
        for (int k = 0; k < 3; ++k) {
            const int idx = 192 * w + 64 * k + lane;  // float4 index within window
            __builtin_amdgcn_global_load_lds(
                (const __attribute__((address_space(1))) void*)(src + (size_t)idx * 4),
                (__attribute__((address_space(3))) void*)(&nbr[idx * 4]),
                16, 0, 0);
        }
    }

    // ---- own normals for all 4 quarters (in flight alongside staging) ----
    float3 own[4];
#pragma unroll
    for (int m = 0; m < 4; ++m) {
        own[m] = *(const float3*)(nbase + (size_t)(u0 + tid + m * QTR) * 3);
    }

    // ---- full M[3][4][4] (uniform scalar math) ----
    const float c0 = 0.429043f, c1 = 0.511664f, c2 = 0.743125f,
                c3 = 0.886227f, c4 = 0.247708f;
    float M[3][4][4];
#pragma unroll
    for (int c = 0; c < 3; ++c) {
        const float L0 = sh[9*c+0], L1 = sh[9*c+1], L2 = sh[9*c+2];
        const float L3 = sh[9*c+3], L4 = sh[9*c+4], L5 = sh[9*c+5];
        const float L6 = sh[9*c+6], L7 = sh[9*c+7], L8 = sh[9*c+8];
        M[c][0][0] = c0*L8;  M[c][0][1] = c0*L4;  M[c][0][2] = c0*L7;  M[c][0][3] = c1*L3;
        M[c][1][0] = c0*L4;  M[c][1][1] = -c0*L8; M[c][1][2] = c0*L5;  M[c][1][3] = c1*L1;
        M[c][2][0] = c0*L7;  M[c][2][1] = c0*L5;  M[c][2][2] = c2*L6;  M[c][2][3] = c1*L2;
        M[c][3][0] = c1*L3;  M[c][3][1] = c1*L1;  M[c][3][2] = c1*L2;  M[c][3][3] = c3*L0 - c4*L6;
    }

    // ---- wait for this wave's staging + own loads (wave-local; no barrier) ----
    asm volatile("s_waitcnt vmcnt(0)" ::: "memory");
    __builtin_amdgcn_sched_barrier(0);

    // ---- neighbors: 3x ds_read_b128 at 48B lane stride (conflict-free) ----
    const float4* lp = (const float4*)(&nbr[12 * tid]);
    const float4 q0 = lp[0], q1 = lp[1], q2 = lp[2];
    const float ng[12] = {q0.x,q0.y,q0.z,q0.w, q1.x,q1.y,q1.z,q1.w, q2.x,q2.y,q2.z,q2.w};

    float* obase = out + (size_t)b * (SH_V * 3);

#pragma unroll
    for (int m = 0; m < 4; ++m) {
        const float nx = own[m].x, ny = own[m].y, nz = own[m].z;
        const float dx = fmaf(nx, ng[0], fmaf(ny, ng[3], fmaf(nz, ng[6], ng[9])));
        const float dy = fmaf(nx, ng[1], fmaf(ny, ng[4], fmaf(nz, ng[7], ng[10])));
        const float dz = fmaf(nx, ng[2], fmaf(ny, ng[5], fmaf(nz, ng[8], ng[11])));
        const float dw = nx + ny + nz + 1.0f;

        float* op = obase + (size_t)(u0 + tid + m * QTR) * 3;
        __builtin_nontemporal_store(
            fmaf(M[0][m][0], dx, fmaf(M[0][m][1], dy, fmaf(M[0][m][2], dz, M[0][m][3] * dw))), op);
        __builtin_nontemporal_store(
            fmaf(M[1][m][0], dx, fmaf(M[1][m][1], dy, fmaf(M[1][m][2], dz, M[1][m][3] * dw))), op + 1);
        __builtin_nontemporal_store(
            fmaf(M[2][m][0], dx, fmaf(M[2][m][1], dy, fmaf(M[2][m][2], dz, M[2][m][3] * dw))), op + 2);
    }
}

extern "C" void kernel_launch(void* const* d_in, const int* in_sizes, int n_in,
                              void* d_out, int out_size, void* d_ws, size_t ws_size,
                              hipStream_t stream) {
    const float* normals = (const float*)d_in[1];   // B*V*3
    const float* sh      = (const float*)d_in[2];   // 27
    float* out           = (float*)d_out;           // B*V*3

    const int grid = SH_B * (QTR / 256);            // 4096 blocks

    // Launch 1: the real output.
    sh_lighting_kernel<<<grid, 256, 0, stream>>>(normals, sh, out);

    // Launch 2: full-size dummy (diagnostic). Writing d_ws if it fits, else
    // rewriting d_out with identical values (idempotent -> still correct).
    float* dummy = (ws_size >= (size_t)SH_B * SH_V * 3 * sizeof(float))
                       ? (float*)d_ws : out;
    sh_lighting_kernel<<<grid, 256, 0, stream>>>(normals, sh, dummy);
}

// Round 7
// 25.929 us; speedup vs baseline: 1.8368x; 1.8368x over previous
//
#include <hip/hip_runtime.h>

// SphericalHarmonicsLighting — B=16, V=262144 (2^18), QTR = V/4 = 65536
// E[b,v,c] = sum_j Nown[j] * (M[c][row i] . Naug[b, (4v mod V)+j]),
//   i = v>>16 (quarter), Naug = (nx,ny,nz,1)  [torch .view() quirk]
//
// R7 = R6 with the compile fix: NT store uses a native ext_vector float4
// (HIP_vector_type<float,4> is a struct -> rejected by __builtin_nontemporal_store).
//
// R6 theory recap: make ALL global traffic fully packed (16B/lane dwordx4).
//  - window  [4u0, 4u0+1024): 12KB staged packed via global_load_lds
//  - own normals (4 quarters x 256 verts x 12B = 12KB): staged packed too
//  - results transposed through 12KB LDS; wave w stores quarter w's contiguous
//    3KB region as packed nontemporal dwordx4
// LDS 36KB/block -> 4 blocks/CU (16 waves/CU). Two barriers (proven free, R2).

#define SH_V 262144
#define SH_B 16
#define QTR  65536

typedef float f32x4 __attribute__((ext_vector_type(4)));

__global__ __launch_bounds__(256, 4) void sh_lighting_kernel(
    const float* __restrict__ normals,   // [B, V, 3]
    const float* __restrict__ sh,        // [27]
    float* __restrict__ out)             // [B, V, 3]
{
    __shared__ float nbr [3072];   // neighbor window: 1024 verts * 3
    __shared__ float ownb[3072];   // own normals: 4 quarters * 256 verts * 3
    __shared__ float res [3072];   // results:     4 quarters * 256 verts * 3

    const int tid  = threadIdx.x;
    const int lane = tid & 63;
    const int w    = tid >> 6;           // wave 0..3
    const int blk  = blockIdx.x;
    const int b    = blk >> 8;           // 256 u-blocks per batch image
    const int ublk = blk & 255;
    const int u0   = ublk << 8;          // u in [u0, u0+256)
    const int nb0  = u0 << 2;            // neighbor window base = 4*u0 (< V)

    const float* nbase = normals + (size_t)b * (SH_V * 3);

    // ---- stage neighbor window: 768 float4s, fully packed ----
    {
        const float* src = nbase + (size_t)nb0 * 3;
#pragma unroll
        for (int k = 0; k < 3; ++k) {
            const int idx = k * 256 + tid;
            __builtin_amdgcn_global_load_lds(
                (const __attribute__((address_space(1))) void*)(src + (size_t)idx * 4),
                (__attribute__((address_space(3))) void*)(&nbr[idx * 4]),
                16, 0, 0);
        }
    }

    // ---- stage own normals: 4 quarters x 192 float4s, packed (per-lane src addr) ----
    {
#pragma unroll
        for (int k = 0; k < 3; ++k) {
            const int g = k * 256 + tid;        // 0..767
            const int m = g / 192;              // quarter 0..3
            const int j = g - m * 192;          // float4 index within quarter block
            const float* src = nbase + ((size_t)(u0 + m * QTR) * 3 + (size_t)j * 4);
            __builtin_amdgcn_global_load_lds(
                (const __attribute__((address_space(1))) void*)src,
                (__attribute__((address_space(3))) void*)(&ownb[g * 4]),
                16, 0, 0);
        }
    }

    // ---- M[3][4][4] (uniform scalar math) ----
    const float c0 = 0.429043f, c1 = 0.511664f, c2 = 0.743125f,
                c3 = 0.886227f, c4 = 0.247708f;
    float M[3][4][4];
#pragma unroll
    for (int c = 0; c < 3; ++c) {
        const float L0 = sh[9*c+0], L1 = sh[9*c+1], L2 = sh[9*c+2];
        const float L3 = sh[9*c+3], L4 = sh[9*c+4], L5 = sh[9*c+5];
        const float L6 = sh[9*c+6], L7 = sh[9*c+7], L8 = sh[9*c+8];
        M[c][0][0] = c0*L8;  M[c][0][1] = c0*L4;  M[c][0][2] = c0*L7;  M[c][0][3] = c1*L3;
        M[c][1][0] = c0*L4;  M[c][1][1] = -c0*L8; M[c][1][2] = c0*L5;  M[c][1][3] = c1*L1;
        M[c][2][0] = c0*L7;  M[c][2][1] = c0*L5;  M[c][2][2] = c2*L6;  M[c][2][3] = c1*L2;
        M[c][3][0] = c1*L3;  M[c][3][1] = c1*L1;  M[c][3][2] = c1*L2;  M[c][3][3] = c3*L0 - c4*L6;
    }

    __syncthreads();   // drains staging (vmcnt(0)) for cross-wave ownb sharing

    // ---- neighbors: 3x ds_read_b128 at 48B lane stride (bank floor) ----
    const f32x4* lp = (const f32x4*)(&nbr[12 * tid]);
    const f32x4 q0 = lp[0], q1 = lp[1], q2 = lp[2];
    const float ng[12] = {q0.x,q0.y,q0.z,q0.w, q1.x,q1.y,q1.z,q1.w, q2.x,q2.y,q2.z,q2.w};

    // ---- compute 4 outputs, write to res (LDS) ----
#pragma unroll
    for (int m = 0; m < 4; ++m) {
        const float nx = ownb[m*768 + 3*tid + 0];
        const float ny = ownb[m*768 + 3*tid + 1];
        const float nz = ownb[m*768 + 3*tid + 2];
        const float dx = fmaf(nx, ng[0], fmaf(ny, ng[3], fmaf(nz, ng[6], ng[9])));
        const float dy = fmaf(nx, ng[1], fmaf(ny, ng[4], fmaf(nz, ng[7], ng[10])));
        const float dz = fmaf(nx, ng[2], fmaf(ny, ng[5], fmaf(nz, ng[8], ng[11])));
        const float dw = nx + ny + nz + 1.0f;

        res[m*768 + 3*tid + 0] =
            fmaf(M[0][m][0], dx, fmaf(M[0][m][1], dy, fmaf(M[0][m][2], dz, M[0][m][3] * dw)));
        res[m*768 + 3*tid + 1] =
            fmaf(M[1][m][0], dx, fmaf(M[1][m][1], dy, fmaf(M[1][m][2], dz, M[1][m][3] * dw)));
        res[m*768 + 3*tid + 2] =
            fmaf(M[2][m][0], dx, fmaf(M[2][m][1], dy, fmaf(M[2][m][2], dz, M[2][m][3] * dw)));
    }

    __syncthreads();   // res complete before cross-wave packed store

    // ---- packed NT stores: wave w stores quarter w's contiguous 3KB region ----
    {
        float* obase = out + (size_t)b * (SH_V * 3) + (size_t)(u0 + w * QTR) * 3;
        const f32x4* rp = (const f32x4*)(&res[w * 768]);
#pragma unroll
        for (int k = 0; k < 3; ++k) {
            const int j = k * 64 + lane;            // float4 idx 0..191 in quarter
            const f32x4 val = rp[j];                // ds_read_b128, 16B stride
            __builtin_nontemporal_store(val, (f32x4*)(obase + (size_t)j * 4));
        }
    }
}

extern "C" void kernel_launch(void* const* d_in, const int* in_sizes, int n_in,
                              void* d_out, int out_size, void* d_ws, size_t ws_size,
                              hipStream_t stream) {
    // d_in[0] = light (3) -- unused by the reference computation
    const float* normals = (const float*)d_in[1];   // B*V*3
    const float* sh      = (const float*)d_in[2];   // 27
    float* out           = (float*)d_out;           // B*V*3

    const int grid = SH_B * (QTR / 256);            // 4096 blocks
    sh_lighting_kernel<<<grid, 256, 0, stream>>>(normals, sh, out);
}